// Round 1
// baseline (110.040 us; speedup 1.0000x reference)
//
#include <hip/hip_runtime.h>
#include <math.h>

#define NN 128
#define MLINKS 256
#define KK 5
#define HID 128
#define EF 17
#define BATCH 16
#define IN_DIM 86721
#define COMB 33089
#define XSTRIDE 33104              // COMB padded to multiple of 16 floats (float4-aligned rows)
#define NBLK2 259                  // ceil(33089/128)

// input-row offsets
#define OFF_SD 0
#define OFF_SLOTS 256
#define OFF_SPEC 261
#define OFF_LF 321
#define OFF_BET 4673
#define OFF_ADJ 4801

// x-row offsets (concat order: Hm, source_dest, slots, c_band, l_band, alpha)
#define XO_HM 0
#define XO_SD 16384
#define XO_SLOTS 16640
#define XO_CB 16645
#define XO_LB 16675
#define XO_AL 16705

// ---------------------------------------------------------------------------
// Kernel 1: per-batch front end. One block per batch, 256 threads (4 waves).
// Computes ec, attention scalars, row-softmax alpha (one row per wave,
// shfl butterfly reduces), and writes the full x row into workspace.
// ---------------------------------------------------------------------------
__global__ __launch_bounds__(256) void k_front(const float* __restrict__ in,
                                               const float* __restrict__ WH,
                                               const float* __restrict__ WE,
                                               const float* __restrict__ a_attn,
                                               float* __restrict__ x) {
    const int b = blockIdx.x;
    const int tid = threadIdx.x;
    const float* row = in + (size_t)b * IN_DIM;

    __shared__ float bet_s[NN];
    __shared__ float WH_s[HID];
    __shared__ float ec_s[HID];
    __shared__ float lf_s[EF];
    __shared__ float sab_s[NN];
    __shared__ float sc[3];  // dWH1, dWH2, s_e

    if (tid < NN)  bet_s[tid] = row[OFF_BET + tid];
    if (tid < HID) WH_s[tid]  = WH[tid];
    if (tid < EF) {
        // deterministic per-e mean over the 256 links
        float s = 0.f;
        for (int m = 0; m < MLINKS; ++m) s += row[OFF_LF + m * EF + tid];
        lf_s[tid] = s * (1.0f / 256.0f);
    }
    __syncthreads();

    if (tid < HID) {
        float acc = 0.f;
        #pragma unroll
        for (int e = 0; e < EF; ++e) acc += lf_s[e] * WE[e * HID + tid];
        ec_s[tid] = acc;
    }
    __syncthreads();

    if (tid == 0) {
        float d1 = 0.f, d2 = 0.f, se = 0.f;
        for (int h = 0; h < HID; ++h) {
            d1 += WH_s[h] * a_attn[h];
            d2 += WH_s[h] * a_attn[HID + h];
            se += ec_s[h] * a_attn[2 * HID + h];
        }
        sc[0] = d1; sc[1] = d2; sc[2] = se;
    }
    __syncthreads();

    const float dWH1 = sc[0], dWH2 = sc[1], s_e = sc[2];
    const int wv = tid >> 6, lane = tid & 63;
    const float betA = bet_s[lane], betB = bet_s[lane + 64];
    const float skA = betA * dWH2, skB = betB * dWH2;
    float* xr = x + (size_t)b * XSTRIDE;

    // one attention row per wave; lane handles columns (lane, lane+64)
    for (int i = wv; i < NN; i += 4) {
        const float sq = bet_s[i] * dWH1 + s_e;
        const float adj1 = row[OFF_ADJ + i * NN + lane];
        const float adj2 = row[OFF_ADJ + i * NN + 64 + lane];
        float v1 = (adj1 > 0.f) ? tanhf(sq + skA) : -1e9f;
        float v2 = (adj2 > 0.f) ? tanhf(sq + skB) : -1e9f;
        float m = fmaxf(v1, v2);
        #pragma unroll
        for (int d = 1; d < 64; d <<= 1) m = fmaxf(m, __shfl_xor(m, d));
        float e1 = expf(v1 - m), e2 = expf(v2 - m);
        float s = e1 + e2;
        float sb = e1 * betA + e2 * betB;
        #pragma unroll
        for (int d = 1; d < 64; d <<= 1) {
            s  += __shfl_xor(s, d);
            sb += __shfl_xor(sb, d);
        }
        const float inv = 1.0f / s;
        xr[XO_AL + i * NN + lane]      = e1 * inv;
        xr[XO_AL + i * NN + 64 + lane] = e2 * inv;
        if (lane == 0) sab_s[i] = sb * inv;
    }
    __syncthreads();

    // Hm[i,h] = ec0 * sab[i] * WH[h]
    const float ec0 = ec_s[0];
    for (int idx = tid; idx < NN * HID; idx += 256)
        xr[XO_HM + idx] = ec0 * sab_s[idx >> 7] * WH_s[idx & 127];

    // tails
    xr[XO_SD + tid] = row[OFF_SD + tid];                 // source_dest (256)
    if (tid < KK) xr[XO_SLOTS + tid] = row[OFF_SLOTS + tid];
    if (tid < 30) {
        const int k = tid / 6, c = tid % 6;
        xr[XO_CB + tid] = row[OFF_SPEC + k * 12 + c];        // spectrum[k,0,c]
        xr[XO_LB + tid] = row[OFF_SPEC + k * 12 + 6 + c];    // spectrum[k,1,c]
    }
}

// ---------------------------------------------------------------------------
// Kernel 2: split-K GEMM  partial[p] += x[:, k0:k0+128] @ W0[k0:k0+128, :]
// 259 blocks x 256 threads. float4 W0 loads (16B/lane), x chunk in LDS.
// Deterministic: each block writes its own partial slab.
// ---------------------------------------------------------------------------
__global__ __launch_bounds__(256) void k_gemm0(const float* __restrict__ x,
                                               const float* __restrict__ W0,
                                               float* __restrict__ part) {
    const int p = blockIdx.x;
    const int k0 = p * 128;
    const int klen = (COMB - k0 < 128) ? (COMB - k0) : 128;
    const int tid = threadIdx.x;

    __shared__ float xs[BATCH][128];
    for (int idx = tid; idx < BATCH * 128; idx += 256) {
        const int bb = idx >> 7, kk = idx & 127;
        xs[bb][kk] = (kk < klen) ? x[(size_t)bb * XSTRIDE + k0 + kk] : 0.f;
    }
    __syncthreads();

    const int g = tid >> 5;          // 0..7 -> batches 2g, 2g+1
    const int c = tid & 31;          // float4 column group (covers h = 4c..4c+3)
    float4 acc0 = {0.f, 0.f, 0.f, 0.f};
    float4 acc1 = {0.f, 0.f, 0.f, 0.f};
    const float4* __restrict__ W0v =
        reinterpret_cast<const float4*>(W0 + (size_t)k0 * HID);

    for (int kk = 0; kk < klen; ++kk) {
        const float4 w = W0v[kk * 32 + c];
        const float xa = xs[2 * g][kk];
        const float xb = xs[2 * g + 1][kk];
        acc0.x += xa * w.x; acc0.y += xa * w.y; acc0.z += xa * w.z; acc0.w += xa * w.w;
        acc1.x += xb * w.x; acc1.y += xb * w.y; acc1.z += xb * w.z; acc1.w += xb * w.w;
    }

    float4* pp = reinterpret_cast<float4*>(part + (size_t)p * (BATCH * HID));
    pp[(2 * g) * 32 + c]     = acc0;
    pp[(2 * g + 1) * 32 + c] = acc1;
}

// ---------------------------------------------------------------------------
// Kernel 3: reduce partials + bias + ReLU -> y0 (16x128)
// ---------------------------------------------------------------------------
__global__ __launch_bounds__(256) void k_reduce(const float* __restrict__ part,
                                                const float* __restrict__ b0,
                                                float* __restrict__ y0) {
    const int o = blockIdx.x * 256 + threadIdx.x;  // 0..2047
    float s = 0.f;
    for (int p = 0; p < NBLK2; ++p) s += part[(size_t)p * (BATCH * HID) + o];
    s += b0[o & 127];
    y0[o] = fmaxf(s, 0.f);
}

// ---------------------------------------------------------------------------
// Kernel 4: 4 chained 128x128 ReLU layers, single block, LDS double buffer.
// ---------------------------------------------------------------------------
__global__ __launch_bounds__(256) void k_tail(const float* __restrict__ y0,
                                              const float* __restrict__ Wr,
                                              const float* __restrict__ br,
                                              float* __restrict__ out) {
    __shared__ float xb[2][BATCH][HID];
    const int tid = threadIdx.x;
    for (int idx = tid; idx < BATCH * HID; idx += 256)
        xb[0][idx >> 7][idx & 127] = y0[idx];
    __syncthreads();

    const int h = tid & 127, g = tid >> 7;  // g=0 -> batches 0..7, g=1 -> 8..15
    int cur = 0;
    for (int L = 0; L < 4; ++L) {
        float acc[8];
        #pragma unroll
        for (int j = 0; j < 8; ++j) acc[j] = br[L * HID + h];
        const float* __restrict__ W = Wr + (size_t)L * HID * HID;
        for (int k = 0; k < HID; ++k) {
            const float w = W[k * HID + h];
            #pragma unroll
            for (int j = 0; j < 8; ++j) acc[j] += xb[cur][g * 8 + j][k] * w;
        }
        #pragma unroll
        for (int j = 0; j < 8; ++j)
            xb[cur ^ 1][g * 8 + j][h] = fmaxf(acc[j], 0.f);
        cur ^= 1;
        __syncthreads();
    }
    for (int idx = tid; idx < BATCH * HID; idx += 256)
        out[idx] = xb[cur][idx >> 7][idx & 127];
}

// ---------------------------------------------------------------------------
extern "C" void kernel_launch(void* const* d_in, const int* in_sizes, int n_in,
                              void* d_out, int out_size, void* d_ws, size_t ws_size,
                              hipStream_t stream) {
    const float* in     = (const float*)d_in[0];
    const float* WH     = (const float*)d_in[1];
    const float* WE     = (const float*)d_in[2];
    const float* a_attn = (const float*)d_in[3];
    const float* W0     = (const float*)d_in[4];
    const float* b0     = (const float*)d_in[5];
    const float* Wr     = (const float*)d_in[6];
    const float* br     = (const float*)d_in[7];
    float* out = (float*)d_out;

    float* ws   = (float*)d_ws;
    float* x    = ws;                                   // 16 * 33104 floats
    float* part = ws + (size_t)BATCH * XSTRIDE;         // 259 * 2048 floats
    float* y0   = part + (size_t)NBLK2 * (BATCH * HID); // 2048 floats

    hipLaunchKernelGGL(k_front, dim3(BATCH), dim3(256), 0, stream,
                       in, WH, WE, a_attn, x);
    hipLaunchKernelGGL(k_gemm0, dim3(NBLK2), dim3(256), 0, stream,
                       x, W0, part);
    hipLaunchKernelGGL(k_reduce, dim3(8), dim3(256), 0, stream,
                       part, b0, y0);
    hipLaunchKernelGGL(k_tail, dim3(1), dim3(256), 0, stream,
                       y0, Wr, br, out);
}

// Round 2
// 92.912 us; speedup vs baseline: 1.1843x; 1.1843x over previous
//
#include <hip/hip_runtime.h>
#include <math.h>

#define NN 128
#define MLINKS 256
#define KK 5
#define HID 128
#define EF 17
#define BATCH 16
#define IN_DIM 86721
#define COMB 33089
#define NBLK2 259                  // ceil(33089/128)
#define XC_STRIDE 16720            // compact x region (16705 floats) padded to /16

// input-row offsets
#define OFF_SD 0
#define OFF_SLOTS 256
#define OFF_SPEC 261
#define OFF_LF 321
#define OFF_BET 4673
#define OFF_ADJ 4801

// compact-x offsets (k >= 16384 region of the concat; ck = k - 16384)
#define XC_SD 0
#define XC_SLOTS 256
#define XC_CB 261
#define XC_LB 291
#define XC_AL 321

// ---------------------------------------------------------------------------
// Kernel 1: per-batch scalars (ec, attention dots) + x tail writes.
// 16 blocks x 128 threads.
// scal[b*4 + {0,1,2,3}] = {dWH1, dWH2, s_e, ec0}
// ---------------------------------------------------------------------------
__global__ __launch_bounds__(128) void k_scal(const float* __restrict__ in,
                                              const float* __restrict__ WH,
                                              const float* __restrict__ WE,
                                              const float* __restrict__ a_attn,
                                              float* __restrict__ xc,
                                              float* __restrict__ scal) {
    const int b = blockIdx.x;
    const int tid = threadIdx.x;
    const float* row = in + (size_t)b * IN_DIM;

    __shared__ float lf_lds[MLINKS * EF];   // 4352 floats
    __shared__ float lfm[EF];
    __shared__ float WH_s[HID];
    __shared__ float ec_s[HID];
    __shared__ float red0[HID], red1[HID], red2[HID];

    for (int i = tid; i < MLINKS * EF; i += 128) lf_lds[i] = row[OFF_LF + i];
    WH_s[tid] = WH[tid];
    __syncthreads();

    if (tid < EF) {
        float s = 0.f;
        for (int m = 0; m < MLINKS; ++m) s += lf_lds[m * EF + tid];
        lfm[tid] = s * (1.0f / 256.0f);
    }
    __syncthreads();

    float ecv = 0.f;
    #pragma unroll
    for (int e = 0; e < EF; ++e) ecv += lfm[e] * WE[e * HID + tid];
    ec_s[tid] = ecv;

    red0[tid] = WH_s[tid] * a_attn[tid];
    red1[tid] = WH_s[tid] * a_attn[HID + tid];
    red2[tid] = ecv * a_attn[2 * HID + tid];
    __syncthreads();
    for (int s = 64; s > 0; s >>= 1) {
        if (tid < s) {
            red0[tid] += red0[tid + s];
            red1[tid] += red1[tid + s];
            red2[tid] += red2[tid + s];
        }
        __syncthreads();
    }
    if (tid == 0) {
        scal[b * 4 + 0] = red0[0];
        scal[b * 4 + 1] = red1[0];
        scal[b * 4 + 2] = red2[0];
        scal[b * 4 + 3] = ec_s[0];
    }

    // x tails (compact region)
    float* xr = xc + (size_t)b * XC_STRIDE;
    xr[XC_SD + tid]       = row[OFF_SD + tid];
    xr[XC_SD + 128 + tid] = row[OFF_SD + 128 + tid];
    if (tid < KK) xr[XC_SLOTS + tid] = row[OFF_SLOTS + tid];
    if (tid < 30) {
        const int k = tid / 6, c = tid % 6;
        xr[XC_CB + tid] = row[OFF_SPEC + k * 12 + c];
        xr[XC_LB + tid] = row[OFF_SPEC + k * 12 + 6 + c];
    }
}

// ---------------------------------------------------------------------------
// Kernel 2: attention softmax rows. grid (16 batches, 16 rowgroups) x 256.
// Each wave handles 2 rows. Writes alpha into compact x and sabec[b][i].
// No max-subtraction needed: unmasked scores are tanh in [-1,1]; all-masked
// rows take the guarded uniform path (matches jax softmax of constant row).
// ---------------------------------------------------------------------------
__global__ __launch_bounds__(256) void k_attn(const float* __restrict__ in,
                                              const float* __restrict__ scal,
                                              float* __restrict__ xc,
                                              float* __restrict__ sabec) {
    const int b = blockIdx.x;
    const int rg = blockIdx.y;
    const int tid = threadIdx.x;
    const int wv = tid >> 6, lane = tid & 63;
    const float* row = in + (size_t)b * IN_DIM;

    __shared__ float bet_s[NN];
    __shared__ float scb[4];
    __shared__ float betsum_s;

    if (tid < NN) bet_s[tid] = row[OFF_BET + tid];
    if (tid < 4)  scb[tid] = scal[b * 4 + tid];
    __syncthreads();
    if (wv == 0) {
        float v = bet_s[lane] + bet_s[lane + 64];
        #pragma unroll
        for (int d = 1; d < 64; d <<= 1) v += __shfl_xor(v, d);
        if (lane == 0) betsum_s = v;
    }
    __syncthreads();

    const float d1 = scb[0], d2 = scb[1], se = scb[2], ec0 = scb[3];
    const float betA = bet_s[lane], betB = bet_s[lane + 64];
    const float skA = betA * d2, skB = betB * d2;
    float* xr = xc + (size_t)b * XC_STRIDE;

    #pragma unroll
    for (int r = 0; r < 2; ++r) {
        const int i = rg * 8 + wv * 2 + r;
        const float sq = bet_s[i] * d1 + se;
        const float adj1 = row[OFF_ADJ + i * NN + lane];
        const float adj2 = row[OFF_ADJ + i * NN + 64 + lane];
        float e1 = (adj1 > 0.f) ? expf(tanhf(sq + skA)) : 0.f;
        float e2 = (adj2 > 0.f) ? expf(tanhf(sq + skB)) : 0.f;
        float s  = e1 + e2;
        float sb = e1 * betA + e2 * betB;
        #pragma unroll
        for (int d = 1; d < 64; d <<= 1) {
            s  += __shfl_xor(s, d);
            sb += __shfl_xor(sb, d);
        }
        float inv;
        if (s > 0.f) {
            inv = 1.0f / s;
        } else {            // all-masked row: jax softmax -> uniform 1/128
            e1 = 1.f; e2 = 1.f; sb = betsum_s; inv = 1.0f / 128.0f;
        }
        xr[XC_AL + i * NN + lane]      = e1 * inv;
        xr[XC_AL + i * NN + 64 + lane] = e2 * inv;
        if (lane == 0) sabec[b * NN + i] = ec0 * sb * inv;
    }
}

// ---------------------------------------------------------------------------
// Kernel 3: split-K GEMM over W0. Blocks p<128 synthesize their x-tile from
// the rank-1 Hm (sabec[b][p] * WH[kk]); blocks p>=128 read compact x.
// Also prefetches Wr into L2/L3 for k_tail (keep-alive asm, no DCE).
// ---------------------------------------------------------------------------
__global__ __launch_bounds__(256) void k_gemm0(const float* __restrict__ xcin,
                                               const float* __restrict__ sabec,
                                               const float* __restrict__ WH,
                                               const float* __restrict__ W0,
                                               const float* __restrict__ Wr,
                                               float* __restrict__ part) {
    const int p = blockIdx.x;
    const int tid = threadIdx.x;

    __shared__ float xs[BATCH][128];
    __shared__ float WH_s[HID];
    __shared__ float sab16[BATCH];

    int klen;
    if (p < 128) {
        klen = 128;
        if (tid < HID)   WH_s[tid]  = WH[tid];
        if (tid < BATCH) sab16[tid] = sabec[tid * NN + p];
        __syncthreads();
        for (int idx = tid; idx < BATCH * 128; idx += 256) {
            const int bb = idx >> 7, kk = idx & 127;
            xs[bb][kk] = sab16[bb] * WH_s[kk];
        }
    } else {
        const int k0 = p * 128;
        const int c0 = k0 - 16384;
        klen = (COMB - k0 < 128) ? (COMB - k0) : 128;
        for (int idx = tid; idx < BATCH * 128; idx += 256) {
            const int bb = idx >> 7, kk = idx & 127;
            xs[bb][kk] = (kk < klen) ? xcin[(size_t)bb * XC_STRIDE + c0 + kk] : 0.f;
        }
    }

    // prefetch Wr (256 KB) into L2/L3 so single-block k_tail isn't HBM-cold
    {
        const int pidx = p * 256 + tid;
        if (pidx < 16384) {
            const float4 wp = reinterpret_cast<const float4*>(Wr)[pidx];
            asm volatile("" :: "v"(wp.x), "v"(wp.y), "v"(wp.z), "v"(wp.w));
        }
    }
    __syncthreads();

    const int g = tid >> 5;          // 0..7 -> batches 2g, 2g+1
    const int c = tid & 31;          // float4 column group
    float4 acc0 = {0.f, 0.f, 0.f, 0.f};
    float4 acc1 = {0.f, 0.f, 0.f, 0.f};
    const float4* __restrict__ W0v =
        reinterpret_cast<const float4*>(W0 + (size_t)p * 128 * HID);

    for (int kk = 0; kk < klen; ++kk) {
        const float4 w = W0v[kk * 32 + c];
        const float xa = xs[2 * g][kk];
        const float xb = xs[2 * g + 1][kk];
        acc0.x += xa * w.x; acc0.y += xa * w.y; acc0.z += xa * w.z; acc0.w += xa * w.w;
        acc1.x += xb * w.x; acc1.y += xb * w.y; acc1.z += xb * w.z; acc1.w += xb * w.w;
    }

    float4* pp = reinterpret_cast<float4*>(part + (size_t)p * (BATCH * HID));
    pp[(2 * g) * 32 + c]     = acc0;
    pp[(2 * g + 1) * 32 + c] = acc1;
}

// ---------------------------------------------------------------------------
// Kernel 4: reduce partials + bias + ReLU -> y0. 32 blocks x 256 threads.
// Block handles 64 outputs; 4 p-chunks per output reduced via LDS.
// ---------------------------------------------------------------------------
__global__ __launch_bounds__(256) void k_reduce(const float* __restrict__ part,
                                                const float* __restrict__ b0,
                                                float* __restrict__ y0) {
    const int tid = threadIdx.x;
    const int l = tid & 63;
    const int pc = tid >> 6;                  // 0..3
    const int o = blockIdx.x * 64 + l;        // 0..2047
    const int p0 = pc * 65;
    const int p1 = (p0 + 65 < NBLK2) ? p0 + 65 : NBLK2;
    float s = 0.f;
    for (int p = p0; p < p1; ++p) s += part[(size_t)p * (BATCH * HID) + o];
    __shared__ float red[4][64];
    red[pc][l] = s;
    __syncthreads();
    if (pc == 0) {
        s = red[0][l] + red[1][l] + red[2][l] + red[3][l] + b0[o & 127];
        y0[o] = fmaxf(s, 0.f);
    }
}

// ---------------------------------------------------------------------------
// Kernel 5: 4 chained 128x128 ReLU layers. Single block, 1024 threads
// (16 waves), float4 W loads straight from L2/L3 (prefetched), k-split 2.
// ---------------------------------------------------------------------------
__global__ __launch_bounds__(1024) void k_tail(const float* __restrict__ y0,
                                               const float* __restrict__ Wr,
                                               const float* __restrict__ br,
                                               float* __restrict__ out) {
    __shared__ __align__(16) float xb[2][BATCH][HID];
    __shared__ float4 red[1024];
    const int tid = threadIdx.x;

    for (int i = tid; i < BATCH * HID; i += 1024)
        xb[0][i >> 7][i & 127] = y0[i];
    __syncthreads();

    const int h4 = tid & 31;           // cols 4*h4 .. 4*h4+3
    const int b  = (tid >> 5) & 15;
    const int kh = tid >> 9;           // 0,1 -> k half
    int cur = 0;

    for (int L = 0; L < 4; ++L) {
        const float4* __restrict__ Wv =
            reinterpret_cast<const float4*>(Wr + (size_t)L * HID * HID);
        float4 acc = {0.f, 0.f, 0.f, 0.f};
        const int kbase = kh * 64;
        #pragma unroll 8
        for (int kk = 0; kk < 64; ++kk) {
            const int k = kbase + kk;
            const float4 w = Wv[k * 32 + h4];
            const float xv = xb[cur][b][k];
            acc.x += xv * w.x; acc.y += xv * w.y; acc.z += xv * w.z; acc.w += xv * w.w;
        }
        red[tid] = acc;
        __syncthreads();
        if (kh == 0) {
            const float4 o4 = red[tid + 512];
            const float4 b4 = *reinterpret_cast<const float4*>(br + L * HID + h4 * 4);
            acc.x = fmaxf(acc.x + o4.x + b4.x, 0.f);
            acc.y = fmaxf(acc.y + o4.y + b4.y, 0.f);
            acc.z = fmaxf(acc.z + o4.z + b4.z, 0.f);
            acc.w = fmaxf(acc.w + o4.w + b4.w, 0.f);
            *reinterpret_cast<float4*>(&xb[cur ^ 1][b][h4 * 4]) = acc;
        }
        __syncthreads();
        cur ^= 1;
    }
    for (int i = tid; i < BATCH * HID; i += 1024)
        out[i] = xb[cur][i >> 7][i & 127];
}

// ---------------------------------------------------------------------------
extern "C" void kernel_launch(void* const* d_in, const int* in_sizes, int n_in,
                              void* d_out, int out_size, void* d_ws, size_t ws_size,
                              hipStream_t stream) {
    const float* in     = (const float*)d_in[0];
    const float* WH     = (const float*)d_in[1];
    const float* WE     = (const float*)d_in[2];
    const float* a_attn = (const float*)d_in[3];
    const float* W0     = (const float*)d_in[4];
    const float* b0     = (const float*)d_in[5];
    const float* Wr     = (const float*)d_in[6];
    const float* br     = (const float*)d_in[7];
    float* out = (float*)d_out;

    float* ws    = (float*)d_ws;
    float* xc    = ws;                                    // 16 * 16720
    float* part  = xc + (size_t)BATCH * XC_STRIDE;        // 259 * 2048
    float* y0    = part + (size_t)NBLK2 * (BATCH * HID);  // 2048
    float* sabec = y0 + 2048;                             // 2048
    float* scal  = sabec + 2048;                          // 64

    hipLaunchKernelGGL(k_scal, dim3(BATCH), dim3(128), 0, stream,
                       in, WH, WE, a_attn, xc, scal);
    hipLaunchKernelGGL(k_attn, dim3(BATCH, 16), dim3(256), 0, stream,
                       in, scal, xc, sabec);
    hipLaunchKernelGGL(k_gemm0, dim3(NBLK2), dim3(256), 0, stream,
                       xc, sabec, WH, W0, Wr, part);
    hipLaunchKernelGGL(k_reduce, dim3(32), dim3(256), 0, stream,
                       part, b0, y0);
    hipLaunchKernelGGL(k_tail, dim3(1), dim3(1024), 0, stream,
                       y0, Wr, br, out);
}

// Round 3
// 55.754 us; speedup vs baseline: 1.9737x; 1.6665x over previous
//
#include <hip/hip_runtime.h>
#include <math.h>

#define NN 128
#define MLINKS 256
#define KK 5
#define HID 128
#define EF 17
#define BATCH 16
#define IN_DIM 86721
#define COMB 33089
#define NBLK2 259                  // ceil(33089/128)
#define XC_STRIDE 16720            // compact x region (16705 floats) padded to /16

// input-row offsets
#define OFF_SD 0
#define OFF_SLOTS 256
#define OFF_SPEC 261
#define OFF_LF 321
#define OFF_BET 4673
#define OFF_ADJ 4801

// compact-x offsets (k >= 16384 region of the concat; ck = k - 16384)
#define XC_SD 0
#define XC_SLOTS 256
#define XC_CB 261
#define XC_LB 291
#define XC_AL 321

// ---------------------------------------------------------------------------
// Kernel 1: per-batch scalars (ec, attention dots) + x tail writes.
// 16 blocks x 256 threads.
// scal[b*4 + {0,1,2,3}] = {dWH1, dWH2, s_e, ec0}
// ---------------------------------------------------------------------------
__global__ __launch_bounds__(256) void k_scal(const float* __restrict__ in,
                                              const float* __restrict__ WH,
                                              const float* __restrict__ WE,
                                              const float* __restrict__ a_attn,
                                              float* __restrict__ xc,
                                              float* __restrict__ scal) {
    const int b = blockIdx.x;
    const int tid = threadIdx.x;
    const float* row = in + (size_t)b * IN_DIM;

    __shared__ float lfp[EF][8];
    __shared__ float lfm[EF];
    __shared__ float WH_s[HID];
    __shared__ float red0[HID], red1[HID], red2[HID];

    if (tid < HID) WH_s[tid] = WH[tid];
    // link-feature mean: 136 threads, each sums 32 strided links for one e
    if (tid < EF * 8) {
        const int e = tid >> 3, c = tid & 7;
        float s = 0.f;
        for (int m = c; m < MLINKS; m += 8) s += row[OFF_LF + m * EF + e];
        lfp[e][c] = s;
    }
    __syncthreads();
    if (tid < EF) {
        float s = (lfp[tid][0] + lfp[tid][1]) + (lfp[tid][2] + lfp[tid][3])
                + (lfp[tid][4] + lfp[tid][5]) + (lfp[tid][6] + lfp[tid][7]);
        lfm[tid] = s * (1.0f / 256.0f);
    }
    __syncthreads();

    if (tid < HID) {
        float ecv = 0.f;
        #pragma unroll
        for (int e = 0; e < EF; ++e) ecv += lfm[e] * WE[e * HID + tid];
        red0[tid] = WH_s[tid] * a_attn[tid];
        red1[tid] = WH_s[tid] * a_attn[HID + tid];
        red2[tid] = ecv * a_attn[2 * HID + tid];
        if (tid == 0) scal[b * 4 + 3] = ecv;   // ec0 (h==0 value)
    }
    __syncthreads();
    for (int s = 64; s > 0; s >>= 1) {
        if (tid < s) {
            red0[tid] += red0[tid + s];
            red1[tid] += red1[tid + s];
            red2[tid] += red2[tid + s];
        }
        __syncthreads();
    }
    if (tid == 0) {
        scal[b * 4 + 0] = red0[0];
        scal[b * 4 + 1] = red1[0];
        scal[b * 4 + 2] = red2[0];
    }

    // x tails (compact region)
    float* xr = xc + (size_t)b * XC_STRIDE;
    if (tid < 256) xr[XC_SD + tid] = row[OFF_SD + tid];
    if (tid < KK) xr[XC_SLOTS + tid] = row[OFF_SLOTS + tid];
    if (tid < 30) {
        const int k = tid / 6, c = tid % 6;
        xr[XC_CB + tid] = row[OFF_SPEC + k * 12 + c];
        xr[XC_LB + tid] = row[OFF_SPEC + k * 12 + 6 + c];
    }
}

// ---------------------------------------------------------------------------
// Kernel 2: attention softmax rows. grid (16 batches, 16 rowgroups) x 256.
// Each wave handles 2 rows. Writes alpha into compact x and sabec[b][i].
// No max-subtraction needed: unmasked scores are tanh in [-1,1]; all-masked
// rows take the guarded uniform path (matches jax softmax of constant row).
// ---------------------------------------------------------------------------
__global__ __launch_bounds__(256) void k_attn(const float* __restrict__ in,
                                              const float* __restrict__ scal,
                                              float* __restrict__ xc,
                                              float* __restrict__ sabec) {
    const int b = blockIdx.x;
    const int rg = blockIdx.y;
    const int tid = threadIdx.x;
    const int wv = tid >> 6, lane = tid & 63;
    const float* row = in + (size_t)b * IN_DIM;

    __shared__ float bet_s[NN];
    __shared__ float scb[4];
    __shared__ float betsum_s;

    if (tid < NN) bet_s[tid] = row[OFF_BET + tid];
    if (tid < 4)  scb[tid] = scal[b * 4 + tid];
    __syncthreads();
    if (wv == 0) {
        float v = bet_s[lane] + bet_s[lane + 64];
        #pragma unroll
        for (int d = 1; d < 64; d <<= 1) v += __shfl_xor(v, d);
        if (lane == 0) betsum_s = v;
    }
    __syncthreads();

    const float d1 = scb[0], d2 = scb[1], se = scb[2], ec0 = scb[3];
    const float betA = bet_s[lane], betB = bet_s[lane + 64];
    const float skA = betA * d2, skB = betB * d2;
    float* xr = xc + (size_t)b * XC_STRIDE;

    #pragma unroll
    for (int r = 0; r < 2; ++r) {
        const int i = rg * 8 + wv * 2 + r;
        const float sq = bet_s[i] * d1 + se;
        const float adj1 = row[OFF_ADJ + i * NN + lane];
        const float adj2 = row[OFF_ADJ + i * NN + 64 + lane];
        float e1 = (adj1 > 0.f) ? expf(tanhf(sq + skA)) : 0.f;
        float e2 = (adj2 > 0.f) ? expf(tanhf(sq + skB)) : 0.f;
        float s  = e1 + e2;
        float sb = e1 * betA + e2 * betB;
        #pragma unroll
        for (int d = 1; d < 64; d <<= 1) {
            s  += __shfl_xor(s, d);
            sb += __shfl_xor(sb, d);
        }
        float inv;
        if (s > 0.f) {
            inv = 1.0f / s;
        } else {            // all-masked row: jax softmax -> uniform 1/128
            e1 = 1.f; e2 = 1.f; sb = betsum_s; inv = 1.0f / 128.0f;
        }
        xr[XC_AL + i * NN + lane]      = e1 * inv;
        xr[XC_AL + i * NN + 64 + lane] = e2 * inv;
        if (lane == 0) sabec[b * NN + i] = ec0 * sb * inv;
    }
}

// ---------------------------------------------------------------------------
// Kernel 3: split-K GEMM over W0. Blocks p<128 synthesize their x-tile from
// the rank-1 Hm (sabec[b][p] * WH[kk]); blocks p>=128 read compact x.
// Also prefetches Wr into L2/L3 for k_tail (keep-alive asm, no DCE).
// ---------------------------------------------------------------------------
__global__ __launch_bounds__(256) void k_gemm0(const float* __restrict__ xcin,
                                               const float* __restrict__ sabec,
                                               const float* __restrict__ WH,
                                               const float* __restrict__ W0,
                                               const float* __restrict__ Wr,
                                               float* __restrict__ part) {
    const int p = blockIdx.x;
    const int tid = threadIdx.x;

    __shared__ float xs[BATCH][128];
    __shared__ float WH_s[HID];
    __shared__ float sab16[BATCH];

    int klen;
    if (p < 128) {
        klen = 128;
        if (tid < HID)   WH_s[tid]  = WH[tid];
        if (tid < BATCH) sab16[tid] = sabec[tid * NN + p];
        __syncthreads();
        for (int idx = tid; idx < BATCH * 128; idx += 256) {
            const int bb = idx >> 7, kk = idx & 127;
            xs[bb][kk] = sab16[bb] * WH_s[kk];
        }
    } else {
        const int k0 = p * 128;
        const int c0 = k0 - 16384;
        klen = (COMB - k0 < 128) ? (COMB - k0) : 128;
        for (int idx = tid; idx < BATCH * 128; idx += 256) {
            const int bb = idx >> 7, kk = idx & 127;
            xs[bb][kk] = (kk < klen) ? xcin[(size_t)bb * XC_STRIDE + c0 + kk] : 0.f;
        }
    }

    // prefetch Wr (256 KB) into L2/L3 so k_tail's 16 blocks aren't HBM-cold
    {
        const int pidx = p * 256 + tid;
        if (pidx < 16384) {
            const float4 wp = reinterpret_cast<const float4*>(Wr)[pidx];
            asm volatile("" :: "v"(wp.x), "v"(wp.y), "v"(wp.z), "v"(wp.w));
        }
    }
    __syncthreads();

    const int g = tid >> 5;          // 0..7 -> batches 2g, 2g+1
    const int c = tid & 31;          // float4 column group
    float4 acc0 = {0.f, 0.f, 0.f, 0.f};
    float4 acc1 = {0.f, 0.f, 0.f, 0.f};
    const float4* __restrict__ W0v =
        reinterpret_cast<const float4*>(W0 + (size_t)p * 128 * HID);

    for (int kk = 0; kk < klen; ++kk) {
        const float4 w = W0v[kk * 32 + c];
        const float xa = xs[2 * g][kk];
        const float xb = xs[2 * g + 1][kk];
        acc0.x += xa * w.x; acc0.y += xa * w.y; acc0.z += xa * w.z; acc0.w += xa * w.w;
        acc1.x += xb * w.x; acc1.y += xb * w.y; acc1.z += xb * w.z; acc1.w += xb * w.w;
    }

    float4* pp = reinterpret_cast<float4*>(part + (size_t)p * (BATCH * HID));
    pp[(2 * g) * 32 + c]     = acc0;
    pp[(2 * g + 1) * 32 + c] = acc1;
}

// ---------------------------------------------------------------------------
// Kernel 4: fused partial-reduce + 4-layer ReLU MLP, batch-parallel.
// 16 blocks (one per batch row) x 512 threads (4 k-quarters x 128 h).
// Each block: reduce its batch's 259 partials, then chain the 4 layers
// with LDS ping-pong. W loads are coalesced scalar reads from L2/L3.
// ---------------------------------------------------------------------------
__global__ __launch_bounds__(512) void k_tail(const float* __restrict__ part,
                                              const float* __restrict__ b0,
                                              const float* __restrict__ Wr,
                                              const float* __restrict__ br,
                                              float* __restrict__ out) {
    const int b = blockIdx.x;
    const int tid = threadIdx.x;
    const int h = tid & 127;
    const int q = tid >> 7;            // 0..3

    __shared__ float xs[2][HID];
    __shared__ float red[4][HID];

    // ---- reduce partials for this batch: y0 = relu(sum_p part[p][b][:] + b0)
    const int p0 = q * 65;
    const int p1 = (p0 + 65 < NBLK2) ? p0 + 65 : NBLK2;
    float s = 0.f;
    for (int p = p0; p < p1; ++p)
        s += part[(size_t)p * (BATCH * HID) + b * HID + h];
    red[q][h] = s;
    __syncthreads();
    if (q == 0)
        xs[0][h] = fmaxf(red[0][h] + red[1][h] + red[2][h] + red[3][h] + b0[h], 0.f);
    __syncthreads();

    // ---- 4 layers, k split 4 ways, LDS ping-pong
    int cur = 0;
    for (int L = 0; L < 4; ++L) {
        const float* __restrict__ W = Wr + (size_t)L * HID * HID;
        float acc = 0.f;
        #pragma unroll 8
        for (int kk = 0; kk < 32; ++kk) {
            const int k = q * 32 + kk;
            acc += xs[cur][k] * W[k * HID + h];
        }
        red[q][h] = acc;
        __syncthreads();
        if (q == 0)
            xs[cur ^ 1][h] = fmaxf(red[0][h] + red[1][h] + red[2][h] + red[3][h]
                                   + br[L * HID + h], 0.f);
        cur ^= 1;
        __syncthreads();
    }
    if (tid < HID) out[b * HID + tid] = xs[cur][tid];
}

// ---------------------------------------------------------------------------
extern "C" void kernel_launch(void* const* d_in, const int* in_sizes, int n_in,
                              void* d_out, int out_size, void* d_ws, size_t ws_size,
                              hipStream_t stream) {
    const float* in     = (const float*)d_in[0];
    const float* WH     = (const float*)d_in[1];
    const float* WE     = (const float*)d_in[2];
    const float* a_attn = (const float*)d_in[3];
    const float* W0     = (const float*)d_in[4];
    const float* b0     = (const float*)d_in[5];
    const float* Wr     = (const float*)d_in[6];
    const float* br     = (const float*)d_in[7];
    float* out = (float*)d_out;

    float* ws    = (float*)d_ws;
    float* xc    = ws;                                    // 16 * 16720
    float* part  = xc + (size_t)BATCH * XC_STRIDE;        // 259 * 2048
    float* sabec = part + (size_t)NBLK2 * (BATCH * HID);  // 2048
    float* scal  = sabec + 2048;                          // 64

    hipLaunchKernelGGL(k_scal, dim3(BATCH), dim3(256), 0, stream,
                       in, WH, WE, a_attn, xc, scal);
    hipLaunchKernelGGL(k_attn, dim3(BATCH, 16), dim3(256), 0, stream,
                       in, scal, xc, sabec);
    hipLaunchKernelGGL(k_gemm0, dim3(NBLK2), dim3(256), 0, stream,
                       xc, sabec, WH, W0, Wr, part);
    hipLaunchKernelGGL(k_tail, dim3(BATCH), dim3(512), 0, stream,
                       part, b0, Wr, br, out);
}

// Round 4
// 37.464 us; speedup vs baseline: 2.9373x; 1.4882x over previous
//
#include <hip/hip_runtime.h>
#include <math.h>

#define NN 128
#define MLINKS 256
#define KK 5
#define HID 128
#define EF 17
#define BATCH 16
#define IN_DIM 86721
#define COMB 33089
#define NBLK2 259                  // ceil(33089/128)
#define XC_STRIDE 16720            // compact x region (16705 floats) padded to /16

// input-row offsets
#define OFF_SD 0
#define OFF_SLOTS 256
#define OFF_SPEC 261
#define OFF_LF 321
#define OFF_BET 4673
#define OFF_ADJ 4801

// compact-x offsets (k >= 16384 region of the concat; ck = k - 16384)
#define XC_SD 0
#define XC_SLOTS 256
#define XC_CB 261
#define XC_LB 291
#define XC_AL 321

// ---------------------------------------------------------------------------
// Kernel 1: fused per-batch front end. 16 blocks x 1024 threads (16 waves).
// Phase A: link-feature mean (LDS-staged, coalesced), ec, attention scalars.
// Phase B: 16 waves x 8 softmax rows each; alpha -> xc, sabec[b][i].
// Also writes the small x tails.
// ---------------------------------------------------------------------------
__global__ __launch_bounds__(1024) void k_front(const float* __restrict__ in,
                                                const float* __restrict__ WH,
                                                const float* __restrict__ WE,
                                                const float* __restrict__ a_attn,
                                                float* __restrict__ xc,
                                                float* __restrict__ sabec) {
    const int b = blockIdx.x;
    const int tid = threadIdx.x;
    const float* row = in + (size_t)b * IN_DIM;

    __shared__ float lf_lds[MLINKS * EF];   // 17 KB
    __shared__ float lfp[EF][8];
    __shared__ float lfm[EF];
    __shared__ float WH_s[HID];
    __shared__ float bet_s[NN];
    __shared__ float red0[HID], red1[HID], red2[HID];
    __shared__ float scb[4];                // d1, d2, se, ec0
    __shared__ float betsum_s;

    for (int i = tid; i < MLINKS * EF; i += 1024) lf_lds[i] = row[OFF_LF + i];
    if (tid < HID) WH_s[tid] = WH[tid];
    else if (tid >= 128 && tid < 256) bet_s[tid - 128] = row[OFF_BET + tid - 128];
    __syncthreads();

    // partial link-feature sums (136 threads) + betsum (wave 15)
    if (tid < EF * 8) {
        const int e = tid >> 3, c = tid & 7;
        float s = 0.f;
        #pragma unroll 8
        for (int m = c; m < MLINKS; m += 8) s += lf_lds[m * EF + e];
        lfp[e][c] = s;
    }
    if (tid >= 960) {
        const int lane = tid - 960;
        float v = bet_s[lane] + bet_s[lane + 64];
        #pragma unroll
        for (int d = 1; d < 64; d <<= 1) v += __shfl_xor(v, d);
        if (lane == 0) betsum_s = v;
    }
    __syncthreads();
    if (tid < EF) {
        float s = (lfp[tid][0] + lfp[tid][1]) + (lfp[tid][2] + lfp[tid][3])
                + (lfp[tid][4] + lfp[tid][5]) + (lfp[tid][6] + lfp[tid][7]);
        lfm[tid] = s * (1.0f / 256.0f);
    }
    __syncthreads();
    if (tid < HID) {
        float ecv = 0.f;
        #pragma unroll
        for (int e = 0; e < EF; ++e) ecv += lfm[e] * WE[e * HID + tid];
        red0[tid] = WH_s[tid] * a_attn[tid];
        red1[tid] = WH_s[tid] * a_attn[HID + tid];
        red2[tid] = ecv * a_attn[2 * HID + tid];
        if (tid == 0) scb[3] = ecv;         // ec0
    }
    __syncthreads();
    {
        const int wv = tid >> 6, lane = tid & 63;
        if (wv < 3) {
            const float* ra = (wv == 0) ? red0 : (wv == 1) ? red1 : red2;
            float v = ra[lane] + ra[lane + 64];
            #pragma unroll
            for (int d = 1; d < 64; d <<= 1) v += __shfl_xor(v, d);
            if (lane == 0) scb[wv] = v;
        }
    }
    __syncthreads();

    const float d1 = scb[0], d2 = scb[1], se = scb[2], ec0 = scb[3];
    const float bsum = betsum_s;
    const int wv = tid >> 6, lane = tid & 63;
    const float betA = bet_s[lane], betB = bet_s[lane + 64];
    const float skA = betA * d2, skB = betB * d2;
    float* xr = xc + (size_t)b * XC_STRIDE;

    // 16 waves x 8 rows
    #pragma unroll
    for (int r = 0; r < 8; ++r) {
        const int i = wv * 8 + r;
        const float sq = bet_s[i] * d1 + se;
        const float adj1 = row[OFF_ADJ + i * NN + lane];
        const float adj2 = row[OFF_ADJ + i * NN + 64 + lane];
        float e1 = (adj1 > 0.f) ? expf(tanhf(sq + skA)) : 0.f;
        float e2 = (adj2 > 0.f) ? expf(tanhf(sq + skB)) : 0.f;
        float s  = e1 + e2;
        float sb = e1 * betA + e2 * betB;
        #pragma unroll
        for (int d = 1; d < 64; d <<= 1) {
            s  += __shfl_xor(s, d);
            sb += __shfl_xor(sb, d);
        }
        float inv;
        if (s > 0.f) {
            inv = 1.0f / s;
        } else {            // all-masked row: jax softmax -> uniform 1/128
            e1 = 1.f; e2 = 1.f; sb = bsum; inv = 1.0f / 128.0f;
        }
        xr[XC_AL + i * NN + lane]      = e1 * inv;
        xr[XC_AL + i * NN + 64 + lane] = e2 * inv;
        if (lane == 0) sabec[b * NN + i] = ec0 * sb * inv;
    }

    // x tails
    if (tid < 256) {
        xr[XC_SD + tid] = row[OFF_SD + tid];
    } else if (tid < 261) {
        xr[XC_SLOTS + (tid - 256)] = row[OFF_SLOTS + (tid - 256)];
    } else if (tid < 291) {
        const int idx = tid - 261, k = idx / 6, c = idx % 6;
        xr[XC_CB + idx] = row[OFF_SPEC + k * 12 + c];
    } else if (tid < 321) {
        const int idx = tid - 291, k = idx / 6, c = idx % 6;
        xr[XC_LB + idx] = row[OFF_SPEC + k * 12 + 6 + c];
    }
}

// ---------------------------------------------------------------------------
// Kernel 2: split-K GEMM over W0. 259 blocks x 512 threads (8 waves/CU),
// k split 2 ways within the block (LDS combine). Blocks p<128 synthesize
// their x-tile from the rank-1 Hm (sabec[b][p] * WH[kk]); p>=128 read
// compact x. Constant-length unrolled inner loop except the last block.
// Also prefetches Wr into cache for k_tail (keep-alive asm, no DCE).
// ---------------------------------------------------------------------------
__global__ __launch_bounds__(512) void k_gemm0(const float* __restrict__ xcin,
                                               const float* __restrict__ sabec,
                                               const float* __restrict__ WH,
                                               const float* __restrict__ W0,
                                               const float* __restrict__ Wr,
                                               float* __restrict__ part) {
    const int p = blockIdx.x;
    const int tid = threadIdx.x;

    __shared__ float xs[BATCH][128];
    __shared__ float WH_s[HID];
    __shared__ float sab16[BATCH];
    __shared__ float4 redA[256];
    __shared__ float4 redB[256];

    if (p < 128) {
        if (tid < HID)   WH_s[tid]  = WH[tid];
        else if (tid >= 128 && tid < 144) sab16[tid - 128] = sabec[(tid - 128) * NN + p];
        __syncthreads();
        for (int idx = tid; idx < BATCH * 128; idx += 512) {
            const int bb = idx >> 7, kk = idx & 127;
            xs[bb][kk] = sab16[bb] * WH_s[kk];
        }
    } else {
        const int k0 = p * 128;
        const int c0 = k0 - 16384;
        const int klen = (COMB - k0 < 128) ? (COMB - k0) : 128;
        for (int idx = tid; idx < BATCH * 128; idx += 512) {
            const int bb = idx >> 7, kk = idx & 127;
            xs[bb][kk] = (kk < klen) ? xcin[(size_t)bb * XC_STRIDE + c0 + kk] : 0.f;
        }
    }

    // prefetch Wr (256 KB) into L2/L3 so k_tail isn't HBM-cold
    {
        const int pidx = p * 512 + tid;
        if (pidx < 16384) {
            const float4 wp = reinterpret_cast<const float4*>(Wr)[pidx];
            asm volatile("" :: "v"(wp.x), "v"(wp.y), "v"(wp.z), "v"(wp.w));
        }
    }
    __syncthreads();

    const int kh  = tid >> 8;        // 0/1: k half
    const int sub = tid & 255;
    const int g = sub >> 5;          // 0..7 -> batches 2g, 2g+1
    const int c = sub & 31;          // float4 column group
    float4 acc0 = {0.f, 0.f, 0.f, 0.f};
    float4 acc1 = {0.f, 0.f, 0.f, 0.f};
    const float4* __restrict__ W0v =
        reinterpret_cast<const float4*>(W0 + (size_t)p * 128 * HID);

    if (p != NBLK2 - 1) {
        #pragma unroll 8
        for (int j = 0; j < 64; ++j) {
            const int kk = kh * 64 + j;
            const float4 w = W0v[kk * 32 + c];
            const float xa = xs[2 * g][kk];
            const float xb = xs[2 * g + 1][kk];
            acc0.x += xa * w.x; acc0.y += xa * w.y; acc0.z += xa * w.z; acc0.w += xa * w.w;
            acc1.x += xb * w.x; acc1.y += xb * w.y; acc1.z += xb * w.z; acc1.w += xb * w.w;
        }
    } else {
        const int klen = COMB - (NBLK2 - 1) * 128;   // 65
        const int kend = (kh * 64 + 64 < klen) ? kh * 64 + 64 : klen;
        for (int kk = kh * 64; kk < kend; ++kk) {
            const float4 w = W0v[kk * 32 + c];
            const float xa = xs[2 * g][kk];
            const float xb = xs[2 * g + 1][kk];
            acc0.x += xa * w.x; acc0.y += xa * w.y; acc0.z += xa * w.z; acc0.w += xa * w.w;
            acc1.x += xb * w.x; acc1.y += xb * w.y; acc1.z += xb * w.z; acc1.w += xb * w.w;
        }
    }

    if (kh == 1) { redA[sub] = acc0; redB[sub] = acc1; }
    __syncthreads();
    if (kh == 0) {
        const float4 oA = redA[sub], oB = redB[sub];
        acc0.x += oA.x; acc0.y += oA.y; acc0.z += oA.z; acc0.w += oA.w;
        acc1.x += oB.x; acc1.y += oB.y; acc1.z += oB.z; acc1.w += oB.w;
        float4* pp = reinterpret_cast<float4*>(part + (size_t)p * (BATCH * HID));
        pp[(2 * g) * 32 + c]     = acc0;
        pp[(2 * g + 1) * 32 + c] = acc1;
    }
}

// ---------------------------------------------------------------------------
// Kernel 3: fused partial-reduce + 4-layer ReLU MLP, batch-parallel.
// 16 blocks x 1024 threads (8 k-groups x 128 h). Constant unrolled loops.
// ---------------------------------------------------------------------------
__global__ __launch_bounds__(1024) void k_tail(const float* __restrict__ part,
                                               const float* __restrict__ b0,
                                               const float* __restrict__ Wr,
                                               const float* __restrict__ br,
                                               float* __restrict__ out) {
    const int b = blockIdx.x;
    const int tid = threadIdx.x;
    const int h = tid & 127;
    const int q = tid >> 7;            // 0..7

    __shared__ float xs[2][HID];
    __shared__ float red[8][HID];

    // ---- reduce partials: y0 = relu(sum_p part[p][b][:] + b0)
    {
        const float* pb = part + (size_t)b * HID + h;
        float s = 0.f;
        #pragma unroll 8
        for (int j = 0; j < 32; ++j)
            s += pb[(size_t)(q * 32 + j) * (BATCH * HID)];
        if (q < 3) s += pb[(size_t)(256 + q) * (BATCH * HID)];
        red[q][h] = s;
    }
    __syncthreads();
    if (q == 0) {
        float t = ((red[0][h] + red[1][h]) + (red[2][h] + red[3][h]))
                + ((red[4][h] + red[5][h]) + (red[6][h] + red[7][h])) + b0[h];
        xs[0][h] = fmaxf(t, 0.f);
    }
    __syncthreads();

    // ---- 4 layers, k split 8 ways (16 k's each), LDS ping-pong
    int cur = 0;
    for (int L = 0; L < 4; ++L) {
        const float* __restrict__ W = Wr + (size_t)L * HID * HID;
        float acc = 0.f;
        #pragma unroll
        for (int j = 0; j < 16; ++j) {
            const int k = q * 16 + j;
            acc += xs[cur][k] * W[k * HID + h];
        }
        red[q][h] = acc;
        __syncthreads();
        if (q == 0) {
            float t = ((red[0][h] + red[1][h]) + (red[2][h] + red[3][h]))
                    + ((red[4][h] + red[5][h]) + (red[6][h] + red[7][h]))
                    + br[L * HID + h];
            xs[cur ^ 1][h] = fmaxf(t, 0.f);
        }
        cur ^= 1;
        __syncthreads();
    }
    if (tid < HID) out[b * HID + tid] = xs[cur][tid];
}

// ---------------------------------------------------------------------------
extern "C" void kernel_launch(void* const* d_in, const int* in_sizes, int n_in,
                              void* d_out, int out_size, void* d_ws, size_t ws_size,
                              hipStream_t stream) {
    const float* in     = (const float*)d_in[0];
    const float* WH     = (const float*)d_in[1];
    const float* WE     = (const float*)d_in[2];
    const float* a_attn = (const float*)d_in[3];
    const float* W0     = (const float*)d_in[4];
    const float* b0     = (const float*)d_in[5];
    const float* Wr     = (const float*)d_in[6];
    const float* br     = (const float*)d_in[7];
    float* out = (float*)d_out;

    float* ws    = (float*)d_ws;
    float* xc    = ws;                                    // 16 * 16720
    float* part  = xc + (size_t)BATCH * XC_STRIDE;        // 259 * 2048
    float* sabec = part + (size_t)NBLK2 * (BATCH * HID);  // 2048

    hipLaunchKernelGGL(k_front, dim3(BATCH), dim3(1024), 0, stream,
                       in, WH, WE, a_attn, xc, sabec);
    hipLaunchKernelGGL(k_gemm0, dim3(NBLK2), dim3(512), 0, stream,
                       xc, sabec, WH, W0, Wr, part);
    hipLaunchKernelGGL(k_tail, dim3(BATCH), dim3(1024), 0, stream,
                       part, b0, Wr, br, out);
}